// Round 7
// baseline (820.008 us; speedup 1.0000x reference)
//
#include <hip/hip_runtime.h>
#include <hip/hip_bf16.h>

#define BB 8
#define NN 2048
#define MM 2048
#define FF 64
#define INF __builtin_inff()

typedef __hip_bfloat16 bf16;

// async global->LDS DMA, 16B per lane (per-lane global src, lane-linear LDS dst)
__device__ __forceinline__ void dma16(const void* g, void* l) {
  __builtin_amdgcn_global_load_lds(
      (const __attribute__((address_space(1))) void*)g,
      (__attribute__((address_space(3))) void*)l, 16, 0, 0);
}

// pack two f32 -> bf16x2 dword (RNE), a in low half
__device__ __forceinline__ unsigned pk_bf16x2(float a, float b) {
  union { __hip_bfloat162 h; unsigned u; } cv;
  cv.h.x = __float2bfloat16(a);
  cv.h.y = __float2bfloat16(b);
  return cv.u;
}

// ---------------- row norms: x2[r] = sum_k x[r][k]^2 ----------------
__global__ void norms_k(const float* __restrict__ a, float* __restrict__ o, int rows) {
  int r = blockIdx.x * 256 + threadIdx.x;
  if (r >= rows) return;
  const float4* p = (const float4*)(a + (size_t)r * FF);
  float s = 0.f;
#pragma unroll
  for (int q = 0; q < FF / 4; ++q) {
    float4 v = p[q];
    s = fmaf(v.x, v.x, fmaf(v.y, v.y, fmaf(v.z, v.z, fmaf(v.w, v.w, s))));
  }
  o[r] = s;
}

// ---------------- INF pad (4KB: 256 lanes x 16B) ----------------
__global__ void fillinf_k(unsigned* __restrict__ p) {
  p[blockIdx.x * 256 + threadIdx.x] = 0x7F807F80u;  // bf16 +INF pair
}

// ---------------- dist tile kernel (unchanged; verified round 2) ----------------
// 64x64 (i,j) tile per WG; fp32 dot via LDS; writes dist COLUMN-MAJOR bf16:
// dist[b][col][row], col stride NN.
__global__ __launch_bounds__(256) void dist_k(const float* __restrict__ X,
                                              const float* __restrict__ Y,
                                              const float* __restrict__ x2,
                                              const float* __restrict__ y2,
                                              bf16* __restrict__ dist) {
  __shared__ float xs[64][68];   // x tile row-major; reused as staged dist tile
  __shared__ float ysT[64][68];  // y tile transposed: ysT[k][j]
  const int b = blockIdx.z, i0 = blockIdx.y * 64, j0 = blockIdx.x * 64;
  const int tid = threadIdx.x, tx = tid & 15, ty = tid >> 4;
  const float* Xb = X + ((size_t)b * NN + i0) * FF;
  const float* Yb = Y + ((size_t)b * MM + j0) * FF;
#pragma unroll
  for (int rep = 0; rep < 4; ++rep) {
    int row = rep * 16 + ty;
    float4 vx = *(const float4*)(Xb + row * FF + tx * 4);
    *(float4*)&xs[row][tx * 4] = vx;
    float4 vy = *(const float4*)(Yb + row * FF + tx * 4);
    ysT[tx * 4 + 0][row] = vy.x;
    ysT[tx * 4 + 1][row] = vy.y;
    ysT[tx * 4 + 2][row] = vy.z;
    ysT[tx * 4 + 3][row] = vy.w;
  }
  __syncthreads();

  const int il0 = ty * 4, jl0 = tx * 4;
  float c[4][4] = {};
#pragma unroll
  for (int k = 0; k < FF; ++k) {
    float a0 = xs[il0 + 0][k], a1 = xs[il0 + 1][k], a2 = xs[il0 + 2][k], a3 = xs[il0 + 3][k];
    float4 bv = *(const float4*)&ysT[k][jl0];
    c[0][0] = fmaf(a0, bv.x, c[0][0]); c[0][1] = fmaf(a0, bv.y, c[0][1]);
    c[0][2] = fmaf(a0, bv.z, c[0][2]); c[0][3] = fmaf(a0, bv.w, c[0][3]);
    c[1][0] = fmaf(a1, bv.x, c[1][0]); c[1][1] = fmaf(a1, bv.y, c[1][1]);
    c[1][2] = fmaf(a1, bv.z, c[1][2]); c[1][3] = fmaf(a1, bv.w, c[1][3]);
    c[2][0] = fmaf(a2, bv.x, c[2][0]); c[2][1] = fmaf(a2, bv.y, c[2][1]);
    c[2][2] = fmaf(a2, bv.z, c[2][2]); c[2][3] = fmaf(a2, bv.w, c[2][3]);
    c[3][0] = fmaf(a3, bv.x, c[3][0]); c[3][1] = fmaf(a3, bv.y, c[3][1]);
    c[3][2] = fmaf(a3, bv.z, c[3][2]); c[3][3] = fmaf(a3, bv.w, c[3][3]);
  }

  float x2v[4], y2v[4];
#pragma unroll
  for (int p = 0; p < 4; ++p) x2v[p] = x2[b * NN + i0 + il0 + p];
#pragma unroll
  for (int q = 0; q < 4; ++q) y2v[q] = y2[b * MM + j0 + jl0 + q];
  __syncthreads();  // all xs/ysT dot-reads done; safe to overwrite xs
#pragma unroll
  for (int p = 0; p < 4; ++p) {
    float4 r;
    r.x = sqrtf(fmaxf(x2v[p] + y2v[0] - 2.f * c[p][0], 0.f));
    r.y = sqrtf(fmaxf(x2v[p] + y2v[1] - 2.f * c[p][1], 0.f));
    r.z = sqrtf(fmaxf(x2v[p] + y2v[2] - 2.f * c[p][2], 0.f));
    r.w = sqrtf(fmaxf(x2v[p] + y2v[3] - 2.f * c[p][3], 0.f));
    *(float4*)&xs[il0 + p][jl0] = r;
  }
  __syncthreads();

  // transposed write-out: per column 4 quarter-parts -> 128B contiguous
  const int cl = tid >> 2, part = tid & 3;
  unsigned w8[8];
#pragma unroll
  for (int m = 0; m < 8; ++m) {
    int r0 = part * 16 + m * 2;
    w8[m] = pk_bf16x2(xs[r0][cl], xs[r0 + 1][cl]);
  }
  bf16* dst = dist + ((size_t)b * MM + (j0 + cl)) * NN + i0 + part * 16;
  *(uint4*)dst = make_uint4(w8[0], w8[1], w8[2], w8[3]);
  *(uint4*)(dst + 8) = make_uint4(w8[4], w8[5], w8[6], w8[7]);
}

// ---------------- DP: shfl-systolic, 8 cols/supertick, LDS-DMA staged ----------------
// One 256-thread WG per batch. Global skew s = threadIdx.x owns rows [8s,8s+8);
// wave w holds the contiguous band rows [512w, 512w+512) so 255/256 neighbor
// hand-offs are intra-wave __shfl_up (registers, no barrier dependency); only
// the 3 wave boundaries go through a tiny double-buffered LDS slot + one
// s_barrier per supertick. Supertick t: skew s processes cols [8(t-s), +8).
//
// ROUND-6 POST-MORTEM: vmcnt-covered DMA proved the dist load was NOT the
// stall; the ~1600cy/supertick gap is the chained per-barrier LDS round trips
// (lbuf ds_read -> 32-cell chain -> ds_write -> lgkm -> barrier). This round
// moves the hand-off to shfl and halves the barrier count (8 cols/supertick).

// one column: 8 rows from L[] to C[]. Q = 8 bf16 dist. DIAG/UP from neighbor.
#define COLQ(Q, L, C, DIAG, UP, BP)                                     \
  {                                                                     \
    float d0 = __uint_as_float((Q).x << 16);                            \
    float d1 = __uint_as_float((Q).x & 0xFFFF0000u);                    \
    float d2 = __uint_as_float((Q).y << 16);                            \
    float d3 = __uint_as_float((Q).y & 0xFFFF0000u);                    \
    float d4 = __uint_as_float((Q).z << 16);                            \
    float d5 = __uint_as_float((Q).z & 0xFFFF0000u);                    \
    float d6 = __uint_as_float((Q).w << 16);                            \
    float d7 = __uint_as_float((Q).w & 0xFFFF0000u);                    \
    C[0] = d0 + fminf(fminf(L[0], (DIAG)), (UP));                       \
    C[1] = d1 + fminf(fminf(L[1], L[0]), C[0]);                         \
    C[2] = d2 + fminf(fminf(L[2], L[1]), C[1]);                         \
    C[3] = d3 + fminf(fminf(L[3], L[2]), C[2]);                         \
    C[4] = d4 + fminf(fminf(L[4], L[3]), C[3]);                         \
    C[5] = d5 + fminf(fminf(L[5], L[4]), C[4]);                         \
    C[6] = d6 + fminf(fminf(L[6], L[5]), C[5]);                         \
    C[7] = d7 + fminf(fminf(L[7], L[6]), C[6]);                         \
    BP = C[7];                                                          \
  }

// Supertick: vmcnt wait (slot ready) -> ups via shfl_up (+LDS select for wave
// boundary lane) -> 8 cols compute -> lane63 publishes bottoms -> DMA refill
// slot for t+3 -> lgkm drain -> raw barrier (vmcnt stays outstanding).
#define SUPER(SLOT, PAR)                                                \
  do {                                                                  \
    asm volatile("s_waitcnt vmcnt(16)" ::: "memory");                   \
    __builtin_amdgcn_sched_barrier(0);                                  \
    float4 lb0 = lbuf[(PAR) ^ 1][wvm1][0];                              \
    float4 lb1 = lbuf[(PAR) ^ 1][wvm1][1];                              \
    float s0 = __shfl_up(bprev[0], 1, 64);                              \
    float s1 = __shfl_up(bprev[1], 1, 64);                              \
    float s2 = __shfl_up(bprev[2], 1, 64);                              \
    float s3 = __shfl_up(bprev[3], 1, 64);                              \
    float s4 = __shfl_up(bprev[4], 1, 64);                              \
    float s5 = __shfl_up(bprev[5], 1, 64);                              \
    float s6 = __shfl_up(bprev[6], 1, 64);                              \
    float s7 = __shfl_up(bprev[7], 1, 64);                              \
    float up0 = (lane == 0) ? (wv ? lb0.x : INF) : s0;                  \
    float up1 = (lane == 0) ? (wv ? lb0.y : INF) : s1;                  \
    float up2 = (lane == 0) ? (wv ? lb0.z : INF) : s2;                  \
    float up3 = (lane == 0) ? (wv ? lb0.w : INF) : s3;                  \
    float up4 = (lane == 0) ? (wv ? lb1.x : INF) : s4;                  \
    float up5 = (lane == 0) ? (wv ? lb1.y : INF) : s5;                  \
    float up6 = (lane == 0) ? (wv ? lb1.z : INF) : s6;                  \
    float up7 = (lane == 0) ? (wv ? lb1.w : INF) : s7;                  \
    uint4 q0 = stag[SLOT][0][Lg];                                       \
    uint4 q1 = stag[SLOT][1][Lg];                                       \
    uint4 q2 = stag[SLOT][2][Lg];                                       \
    uint4 q3 = stag[SLOT][3][Lg];                                       \
    uint4 q4 = stag[SLOT][4][Lg];                                       \
    uint4 q5 = stag[SLOT][5][Lg];                                       \
    uint4 q6 = stag[SLOT][6][Lg];                                       \
    uint4 q7 = stag[SLOT][7][Lg];                                       \
    COLQ(q0, pa, pb, topPrev, up0, bprev[0]);                           \
    COLQ(q1, pb, pa, up0, up1, bprev[1]);                               \
    COLQ(q2, pa, pb, up1, up2, bprev[2]);                               \
    COLQ(q3, pb, pa, up2, up3, bprev[3]);                               \
    COLQ(q4, pa, pb, up3, up4, bprev[4]);                               \
    COLQ(q5, pb, pa, up4, up5, bprev[5]);                               \
    COLQ(q6, pa, pb, up5, up6, bprev[6]);                               \
    COLQ(q7, pb, pa, up6, up7, bprev[7]);                               \
    topPrev = up7;                                                      \
    if (lane == 63) {                                                   \
      lbuf[PAR][wv][0] = make_float4(bprev[0], bprev[1], bprev[2], bprev[3]); \
      lbuf[PAR][wv][1] = make_float4(bprev[4], bprev[5], bprev[6], bprev[7]); \
    }                                                                   \
    __builtin_amdgcn_sched_barrier(0);                                  \
    { /* DMA-refill slot for supertick t+3 */                           \
      _Pragma("unroll") for (int ci = 0; ci < 8; ++ci) {                \
        unsigned c = (unsigned)(cbase + ci);                            \
        unsigned off = (c > (unsigned)(MM - 1)) ? infoff                \
                                                : (c << 12) + laneoff;  \
        dma16(dbp + off, &stag[SLOT][ci][Lg]);                          \
      }                                                                 \
      cbase += 8;                                                       \
    }                                                                   \
    asm volatile("s_waitcnt lgkmcnt(0)" ::: "memory");                  \
    __builtin_amdgcn_s_barrier();                                       \
    asm volatile("" ::: "memory");                                      \
  } while (0)

__global__ __launch_bounds__(256, 1) void dp_k(const bf16* __restrict__ dist,
                                               float* __restrict__ out) {
  const int b = blockIdx.x, Lg = threadIdx.x;
  const int lane = Lg & 63, wv = Lg >> 6, wvm1 = (wv + 3) & 3;
  __shared__ uint4 stag[3][8][256];  // 96KB dist staging ring: [slot][col][skew]
  __shared__ float4 lbuf[2][4][2];   // wave-boundary bottoms [parity][wave][half]

  if (Lg < 16) ((float4*)lbuf)[Lg] = make_float4(INF, INF, INF, INF);

  const char* dbp = (const char*)(dist + (size_t)b * NN * MM);
  const unsigned laneoff = (unsigned)Lg * 16u;  // 8 rows * 2B
  const unsigned infoff = (unsigned)((size_t)(BB - b) * NN * MM * 2) + laneoff;

  // prologue: DMA slots 0..2 (superticks 0..2); cols 8(k-Lg)+ci, OOB -> pad
#pragma unroll
  for (int k = 0; k < 3; ++k)
#pragma unroll
    for (int ci = 0; ci < 8; ++ci) {
      unsigned c = (unsigned)(8 * (k - Lg) + ci);
      unsigned off = (c > (unsigned)(MM - 1)) ? infoff : (c << 12) + laneoff;
      dma16(dbp + off, &stag[k][ci][Lg]);
    }

  float pa[8], pb[8], bprev[8];
#pragma unroll
  for (int r = 0; r < 8; ++r) { pa[r] = INF; pb[r] = INF; bprev[r] = INF; }
  float topPrev = (Lg == 0) ? 0.f : INF;  // makes cell (0,0) cand==0 fall out
  int cbase = 24 - 8 * Lg;                // col base for refill target t+3
  __syncthreads();  // orders lbuf init (one-time vmcnt drain acceptable)

  // superticks t = 0..510; skew 255 computes cols 2040..2047 at t=510.
  // slot = t%3, parity = t&1 -> period 6; 510 = 6*85, then one final tick.
  for (int tb = 0; tb < 85; ++tb) {
    SUPER(0, 0);
    SUPER(1, 1);
    SUPER(2, 0);
    SUPER(0, 1);
    SUPER(1, 0);
    SUPER(2, 1);
  }
  SUPER(0, 0);  // t=510
  if (Lg == 255) out[b] = bprev[7];  // D[2047][2047]
}

extern "C" void kernel_launch(void* const* d_in, const int* in_sizes, int n_in,
                              void* d_out, int out_size, void* d_ws, size_t ws_size,
                              hipStream_t stream) {
  const float* X = (const float*)d_in[0];
  const float* Y = (const float*)d_in[1];
  float* out = (float*)d_out;

  float* x2 = (float*)d_ws;                         // BB*NN floats (64KB)
  float* y2 = x2 + BB * NN;                         // BB*MM floats (64KB)
  bf16* dist = (bf16*)((char*)d_ws + 131072);       // BB*NN*MM bf16, col-major
  unsigned* infpad = (unsigned*)(dist + (size_t)BB * NN * MM);  // 4KB INF

  norms_k<<<dim3((BB * NN + 255) / 256), dim3(256), 0, stream>>>(X, x2, BB * NN);
  norms_k<<<dim3((BB * MM + 255) / 256), dim3(256), 0, stream>>>(Y, y2, BB * MM);
  fillinf_k<<<dim3(4), dim3(256), 0, stream>>>(infpad);

  dist_k<<<dim3(MM / 64, NN / 64, BB), dim3(256), 0, stream>>>(X, Y, x2, y2, dist);
  dp_k<<<dim3(BB), dim3(256), 0, stream>>>(dist, out);
}

// Round 8
// 751.604 us; speedup vs baseline: 1.0910x; 1.0910x over previous
//
#include <hip/hip_runtime.h>
#include <hip/hip_bf16.h>

#define BB 8
#define NN 2048
#define MM 2048
#define FF 64
#define INF __builtin_inff()

// diag-major layout, every diagonal 16B-aligned:
// diag d starts at slot off8(d) (16B slots), holds rows i from imin8(d)=imin&~7.
// slots(d) = ((imax+8)>>3) - (imin>>3);  batch stride 526080 slots = 8.4MB.
#define DIAG_SLOTS 526080
#define DIAG_ELEMS (DIAG_SLOTS * 8)

typedef __hip_bfloat16 bf16;

__device__ __forceinline__ int off8slots(int d) {  // # slots before diag d
  if (d <= 2048) { int q = d >> 3, r = d & 7; return d + 4 * q * (q - 1) + q * r; }
  int E = d - 2048, X = E + 1, q = X >> 3, r = X & 7;
  return 263168 + 256 * E - (4 * q * (q - 1) + q * r);
}

// async global->LDS DMA, 16B per lane (per-lane global src, lane-linear LDS dst)
__device__ __forceinline__ void dma16(const void* g, void* l) {
  __builtin_amdgcn_global_load_lds(
      (const __attribute__((address_space(1))) void*)g,
      (__attribute__((address_space(3))) void*)l, 16, 0, 0);
}

// ---------------- row norms ----------------
__global__ void norms_k(const float* __restrict__ a, float* __restrict__ o, int rows) {
  int r = blockIdx.x * 256 + threadIdx.x;
  if (r >= rows) return;
  const float4* p = (const float4*)(a + (size_t)r * FF);
  float s = 0.f;
#pragma unroll
  for (int q = 0; q < FF / 4; ++q) {
    float4 v = p[q];
    s = fmaf(v.x, v.x, fmaf(v.y, v.y, fmaf(v.z, v.z, fmaf(v.w, v.w, s))));
  }
  o[r] = s;
}

// ---------------- dist tile kernel: writes diag-major 16B-aligned bf16 ----------------
__global__ __launch_bounds__(256) void dist_k(const float* __restrict__ X,
                                              const float* __restrict__ Y,
                                              const float* __restrict__ x2,
                                              const float* __restrict__ y2,
                                              bf16* __restrict__ dist) {
  __shared__ float xs[64][68];
  __shared__ float ysT[64][68];
  const int b = blockIdx.z, i0 = blockIdx.y * 64, j0 = blockIdx.x * 64;
  const int tid = threadIdx.x, tx = tid & 15, ty = tid >> 4;
  const float* Xb = X + ((size_t)b * NN + i0) * FF;
  const float* Yb = Y + ((size_t)b * MM + j0) * FF;
#pragma unroll
  for (int rep = 0; rep < 4; ++rep) {
    int row = rep * 16 + ty;
    float4 vx = *(const float4*)(Xb + row * FF + tx * 4);
    *(float4*)&xs[row][tx * 4] = vx;
    float4 vy = *(const float4*)(Yb + row * FF + tx * 4);
    ysT[tx * 4 + 0][row] = vy.x;
    ysT[tx * 4 + 1][row] = vy.y;
    ysT[tx * 4 + 2][row] = vy.z;
    ysT[tx * 4 + 3][row] = vy.w;
  }
  __syncthreads();

  const int il0 = ty * 4, jl0 = tx * 4;
  float c[4][4] = {};
#pragma unroll
  for (int k = 0; k < FF; ++k) {
    float a0 = xs[il0 + 0][k], a1 = xs[il0 + 1][k], a2 = xs[il0 + 2][k], a3 = xs[il0 + 3][k];
    float4 bv = *(const float4*)&ysT[k][jl0];
    c[0][0] = fmaf(a0, bv.x, c[0][0]); c[0][1] = fmaf(a0, bv.y, c[0][1]);
    c[0][2] = fmaf(a0, bv.z, c[0][2]); c[0][3] = fmaf(a0, bv.w, c[0][3]);
    c[1][0] = fmaf(a1, bv.x, c[1][0]); c[1][1] = fmaf(a1, bv.y, c[1][1]);
    c[1][2] = fmaf(a1, bv.z, c[1][2]); c[1][3] = fmaf(a1, bv.w, c[1][3]);
    c[2][0] = fmaf(a2, bv.x, c[2][0]); c[2][1] = fmaf(a2, bv.y, c[2][1]);
    c[2][2] = fmaf(a2, bv.z, c[2][2]); c[2][3] = fmaf(a2, bv.w, c[2][3]);
    c[3][0] = fmaf(a3, bv.x, c[3][0]); c[3][1] = fmaf(a3, bv.y, c[3][1]);
    c[3][2] = fmaf(a3, bv.z, c[3][2]); c[3][3] = fmaf(a3, bv.w, c[3][3]);
  }

  float x2v[4], y2v[4];
#pragma unroll
  for (int p = 0; p < 4; ++p) x2v[p] = x2[b * NN + i0 + il0 + p];
#pragma unroll
  for (int q = 0; q < 4; ++q) y2v[q] = y2[b * MM + j0 + jl0 + q];
  __syncthreads();
#pragma unroll
  for (int p = 0; p < 4; ++p) {
    float4 r;
    r.x = sqrtf(fmaxf(x2v[p] + y2v[0] - 2.f * c[p][0], 0.f));
    r.y = sqrtf(fmaxf(x2v[p] + y2v[1] - 2.f * c[p][1], 0.f));
    r.z = sqrtf(fmaxf(x2v[p] + y2v[2] - 2.f * c[p][2], 0.f));
    r.w = sqrtf(fmaxf(x2v[p] + y2v[3] - 2.f * c[p][3], 0.f));
    *(float4*)&xs[il0 + p][jl0] = r;
  }
  __syncthreads();

  // diag-major write-out (r1 pattern, 8-aligned layout)
  const int lane = tid & 63, w = tid >> 6;
  bf16* db = dist + (size_t)b * DIAG_ELEMS;
#pragma unroll
  for (int s = 0; s < 16; ++s) {
    int cdi = w * 16 + s;
    int jl = (cdi - lane) & 63;
    int d = i0 + j0 + lane + jl;
    int imin8 = (d > 2047) ? (((d - 2047) >> 3) << 3) : 0;
    int pos = off8slots(d) * 8 + (i0 + lane) - imin8;
    db[pos] = __float2bfloat16(xs[lane][jl]);
  }
}

// ---------------- DP: anti-diagonal supertick (8 diags), wave-skewed ----------------
// 256 threads/WG, one WG per batch. Lane Lg owns rows [8Lg, 8Lg+8). Wave w at
// supertick t computes diags 8(t-w)..+7 (wave skew -> cross-wave boundary data
// comes from the PREVIOUS supertick via 3-epoch lbuf). Per step: one contiguous
// 4KB diagonal read (16 lines/wave, coalesced), one shfl_up, 8 independent
// cells (no intra-step chain). No validity guards: top-invalid cells satisfy
// cur = garbage_finite + min3(INF,..) = INF inductively; bottom-invalid
// garbage is never read by valid cells (only j-1 direction reads). Only (0,0)
// needs the one-time cand=0 injection.

#define STEP(K, P, PP, B1, B2)                                          \
  {                                                                     \
    uint4 q = stag[SLOT][K][Lg];                                        \
    float bNew = __shfl_up(P[7], 1, 64);                                \
    float bp1 = (lane == 0) ? (B1) : bNew;                              \
    float bp2 = (lane == 0) ? (B2) : bPrev;                             \
    float d0 = __uint_as_float(q.x << 16);                              \
    float d1 = __uint_as_float(q.x & 0xFFFF0000u);                      \
    float d2 = __uint_as_float(q.y << 16);                              \
    float d3 = __uint_as_float(q.y & 0xFFFF0000u);                      \
    float d4 = __uint_as_float(q.z << 16);                              \
    float d5 = __uint_as_float(q.z & 0xFFFF0000u);                      \
    float d6 = __uint_as_float(q.w << 16);                              \
    float d7 = __uint_as_float(q.w & 0xFFFF0000u);                      \
    PP[7] = d7 + fminf(fminf(P[7], P[6]), PP[6]);                       \
    PP[6] = d6 + fminf(fminf(P[6], P[5]), PP[5]);                       \
    PP[5] = d5 + fminf(fminf(P[5], P[4]), PP[4]);                       \
    PP[4] = d4 + fminf(fminf(P[4], P[3]), PP[3]);                       \
    PP[3] = d3 + fminf(fminf(P[3], P[2]), PP[2]);                       \
    PP[2] = d2 + fminf(fminf(P[2], P[1]), PP[1]);                       \
    PP[1] = d1 + fminf(fminf(P[1], P[0]), PP[0]);                       \
    float c0 = fminf(fminf(P[0], bp1), bp2);                            \
    if (FIRST && (K) == 0) { if (Lg == 0) c0 = 0.f; }                   \
    PP[0] = d0 + c0;                                                    \
    bPrev = bNew;                                                       \
    pub[K] = PP[7];                                                     \
  }

template <int SLOT, bool FIRST>
__device__ __forceinline__ void supertick(const char* dbp,
                                          uint4 (*stag)[8][256],
                                          float (*lbuf)[4][8],
                                          float (&A)[8], float (&B)[8],
                                          float& bPrev, int& dpf, int& offb,
                                          float* pub, int Lg, int lane, int wv,
                                          int wvm1) {
  asm volatile("s_waitcnt vmcnt(16)" ::: "memory");
  __builtin_amdgcn_sched_barrier(0);
  constexpr int PREV = (SLOT + 2) % 3, M2 = (SLOT + 1) % 3;
  float pv0 = lbuf[PREV][wvm1][0], pv1 = lbuf[PREV][wvm1][1];
  float pv2 = lbuf[PREV][wvm1][2], pv3 = lbuf[PREV][wvm1][3];
  float pv4 = lbuf[PREV][wvm1][4], pv5 = lbuf[PREV][wvm1][5];
  float pv6 = lbuf[PREV][wvm1][6];
  float m26 = lbuf[M2][wvm1][6], m27 = lbuf[M2][wvm1][7];
  if (wv == 0) {  // row boundary i=-1: always INF
    pv0 = pv1 = pv2 = pv3 = pv4 = pv5 = pv6 = INF;
    m26 = m27 = INF;
  }
  STEP(0, A, B, m27, m26);
  STEP(1, B, A, pv0, m27);
  STEP(2, A, B, pv1, pv0);
  STEP(3, B, A, pv2, pv1);
  STEP(4, A, B, pv3, pv2);
  STEP(5, B, A, pv4, pv3);
  STEP(6, A, B, pv5, pv4);
  STEP(7, B, A, pv6, pv5);
  if (lane == 63) {
    *(float4*)&lbuf[SLOT][wv][0] = make_float4(pub[0], pub[1], pub[2], pub[3]);
    *(float4*)&lbuf[SLOT][wv][4] = make_float4(pub[4], pub[5], pub[6], pub[7]);
  }
  asm volatile("s_waitcnt lgkmcnt(0)" ::: "memory");  // drain reads+publish
  __builtin_amdgcn_sched_barrier(0);
#pragma unroll
  for (int k = 0; k < 8; ++k) {  // DMA-refill slot SLOT for supertick t+3
    int im = (dpf > 2047) ? (dpf - 2047) : 0;
    bool ok = (unsigned)dpf <= 4094u;
    unsigned Ab = ok ? (unsigned)(offb - ((im >> 3) << 4)) : 0u;
    dma16(dbp + Ab + (unsigned)Lg * 16u, &stag[SLOT][k][Lg]);
    offb += ok ? ((dpf < 2048 ? (dpf >> 3) + 1 : 256 - ((dpf - 2047) >> 3)) << 4) : 0;
    ++dpf;
  }
  __builtin_amdgcn_s_barrier();
  asm volatile("" ::: "memory");
}

__global__ __launch_bounds__(256, 1) void dp_k(const bf16* __restrict__ dist,
                                               float* __restrict__ out) {
  const int b = blockIdx.x, Lg = threadIdx.x;
  const int lane = Lg & 63, wv = Lg >> 6, wvm1 = (wv + 3) & 3;
  __shared__ uint4 stag[3][8][256];  // 96KB: [slot][step][lane], 16B each
  __shared__ float lbuf[3][4][8];    // wave-boundary pubs, 3 epochs (t%3)

  if (Lg < 96) ((float*)lbuf)[Lg] = INF;

  const char* dbp = (const char*)(dist + (size_t)b * DIAG_ELEMS);
  int dpf = -8 * wv;  // prefetch diag cursor (wave-skewed)
  int offb = 0;       // 16*off8slots(max(dpf,0))
  // prologue: fill slots 0..2 (superticks 0..2)
#pragma unroll
  for (int k3 = 0; k3 < 24; ++k3) {
    int im = (dpf > 2047) ? (dpf - 2047) : 0;
    bool ok = (unsigned)dpf <= 4094u;
    unsigned Ab = ok ? (unsigned)(offb - ((im >> 3) << 4)) : 0u;
    dma16(dbp + Ab + (unsigned)Lg * 16u, &stag[k3 >> 3][k3 & 7][Lg]);
    offb += ok ? ((dpf < 2048 ? (dpf >> 3) + 1 : 256 - ((dpf - 2047) >> 3)) << 4) : 0;
    ++dpf;
  }

  float A[8], B[8], pub[8];
#pragma unroll
  for (int r = 0; r < 8; ++r) { A[r] = INF; B[r] = INF; }
  float bPrev = INF;
  __syncthreads();  // lbuf init + prologue DMA drain (one-time)

  // superticks t=0..514; wave 3 computes diag 4094 at t=514 step 6 (-> B).
  supertick<0, true>(dbp, stag, lbuf, A, B, bPrev, dpf, offb, pub, Lg, lane, wv, wvm1);
  supertick<1, false>(dbp, stag, lbuf, A, B, bPrev, dpf, offb, pub, Lg, lane, wv, wvm1);
  supertick<2, false>(dbp, stag, lbuf, A, B, bPrev, dpf, offb, pub, Lg, lane, wv, wvm1);
  for (int tb = 0; tb < 170; ++tb) {  // t = 3..512
    supertick<0, false>(dbp, stag, lbuf, A, B, bPrev, dpf, offb, pub, Lg, lane, wv, wvm1);
    supertick<1, false>(dbp, stag, lbuf, A, B, bPrev, dpf, offb, pub, Lg, lane, wv, wvm1);
    supertick<2, false>(dbp, stag, lbuf, A, B, bPrev, dpf, offb, pub, Lg, lane, wv, wvm1);
  }
  supertick<0, false>(dbp, stag, lbuf, A, B, bPrev, dpf, offb, pub, Lg, lane, wv, wvm1);  // 513
  supertick<1, false>(dbp, stag, lbuf, A, B, bPrev, dpf, offb, pub, Lg, lane, wv, wvm1);  // 514

  if (Lg == 255) out[b] = B[7];  // D[2047][2047] = diag 4094, i=2047
}

extern "C" void kernel_launch(void* const* d_in, const int* in_sizes, int n_in,
                              void* d_out, int out_size, void* d_ws, size_t ws_size,
                              hipStream_t stream) {
  const float* X = (const float*)d_in[0];
  const float* Y = (const float*)d_in[1];
  float* out = (float*)d_out;

  float* x2 = (float*)d_ws;                    // BB*NN floats
  float* y2 = x2 + BB * NN;                    // BB*MM floats
  bf16* dist = (bf16*)((char*)d_ws + 131072);  // BB * 8.4MB diag-major

  norms_k<<<dim3((BB * NN + 255) / 256), dim3(256), 0, stream>>>(X, x2, BB * NN);
  norms_k<<<dim3((BB * MM + 255) / 256), dim3(256), 0, stream>>>(Y, y2, BB * MM);

  dist_k<<<dim3(MM / 64, NN / 64, BB), dim3(256), 0, stream>>>(X, Y, x2, y2, dist);
  dp_k<<<dim3(BB), dim3(256), 0, stream>>>(dist, out);
}

// Round 9
// 456.444 us; speedup vs baseline: 1.7965x; 1.6467x over previous
//
#include <hip/hip_runtime.h>
#include <hip/hip_bf16.h>

#define BB 8
#define NN 2048
#define MM 2048
#define FF 64
#define INF __builtin_inff()

// ---- pipelined-DP geometry ----
// 8 bands of 256 rows per batch; one 64-lane WG per band; lane l owns rows
// 4l..4l+3 of its band. Tick T: lane l processes column-pair p = T - l
// (cols 2p, 2p+1). Stripe t (1KB) holds, for each lane l, 16B = rows 4l..4l+3
// of cols 2(t-l), 2(t-l)+1  -> the wave's tick-t load is lane-linear.
#define STRIPES 1088                 // ticks: 1024 pairs + 64 skew
#define BANDBYTES (STRIPES * 1024)
#define NBANDS 8
#define DIST_BYTES ((size_t)BB * NBANDS * BANDBYTES)   // 71,303,168
#define RING_SLOTS 1088              // float2 per producer tick
#define RING_BYTES ((size_t)BB * NBANDS * RING_SLOTS * 8)

typedef __hip_bfloat16 bf16;

// pack two f32 -> bf16x2 dword (RNE), a in low half
__device__ __forceinline__ unsigned pk_bf16x2(float a, float b) {
  union { __hip_bfloat162 h; unsigned u; } cv;
  cv.h.x = __float2bfloat16(a);
  cv.h.y = __float2bfloat16(b);
  return cv.u;
}

// ---------------- row norms ----------------
__global__ void norms_k(const float* __restrict__ a, float* __restrict__ o, int rows) {
  int r = blockIdx.x * 256 + threadIdx.x;
  if (r >= rows) return;
  const float4* p = (const float4*)(a + (size_t)r * FF);
  float s = 0.f;
#pragma unroll
  for (int q = 0; q < FF / 4; ++q) {
    float4 v = p[q];
    s = fmaf(v.x, v.x, fmaf(v.y, v.y, fmaf(v.z, v.z, fmaf(v.w, v.w, s))));
  }
  o[r] = s;
}

// ---------------- fill dist with 0x7F7F (bf16 = 3.39e38, INF-like, add-safe)
// Covers all skew/garbage slots so the DP needs zero validity guards.
__global__ void fill_k(uint4* __restrict__ p, int n4) {
  int i = blockIdx.x * 256 + threadIdx.x;
  const int stride = gridDim.x * 256;
  const uint4 v = make_uint4(0x7F7F7F7Fu, 0x7F7F7F7Fu, 0x7F7F7F7Fu, 0x7F7F7F7Fu);
  for (; i < n4; i += stride) p[i] = v;
}

// ---------------- dist tile kernel (compute part verified r2-r8) ----------------
__global__ __launch_bounds__(256) void dist_k(const float* __restrict__ X,
                                              const float* __restrict__ Y,
                                              const float* __restrict__ x2,
                                              const float* __restrict__ y2,
                                              char* __restrict__ dist) {
  __shared__ float xs[64][68];
  __shared__ float ysT[64][68];
  const int b = blockIdx.z, i0 = blockIdx.y * 64, j0 = blockIdx.x * 64;
  const int tid = threadIdx.x, tx = tid & 15, ty = tid >> 4;
  const float* Xb = X + ((size_t)b * NN + i0) * FF;
  const float* Yb = Y + ((size_t)b * MM + j0) * FF;
#pragma unroll
  for (int rep = 0; rep < 4; ++rep) {
    int row = rep * 16 + ty;
    float4 vx = *(const float4*)(Xb + row * FF + tx * 4);
    *(float4*)&xs[row][tx * 4] = vx;
    float4 vy = *(const float4*)(Yb + row * FF + tx * 4);
    ysT[tx * 4 + 0][row] = vy.x;
    ysT[tx * 4 + 1][row] = vy.y;
    ysT[tx * 4 + 2][row] = vy.z;
    ysT[tx * 4 + 3][row] = vy.w;
  }
  __syncthreads();

  const int il0 = ty * 4, jl0 = tx * 4;
  float c[4][4] = {};
#pragma unroll
  for (int k = 0; k < FF; ++k) {
    float a0 = xs[il0 + 0][k], a1 = xs[il0 + 1][k], a2 = xs[il0 + 2][k], a3 = xs[il0 + 3][k];
    float4 bv = *(const float4*)&ysT[k][jl0];
    c[0][0] = fmaf(a0, bv.x, c[0][0]); c[0][1] = fmaf(a0, bv.y, c[0][1]);
    c[0][2] = fmaf(a0, bv.z, c[0][2]); c[0][3] = fmaf(a0, bv.w, c[0][3]);
    c[1][0] = fmaf(a1, bv.x, c[1][0]); c[1][1] = fmaf(a1, bv.y, c[1][1]);
    c[1][2] = fmaf(a1, bv.z, c[1][2]); c[1][3] = fmaf(a1, bv.w, c[1][3]);
    c[2][0] = fmaf(a2, bv.x, c[2][0]); c[2][1] = fmaf(a2, bv.y, c[2][1]);
    c[2][2] = fmaf(a2, bv.z, c[2][2]); c[2][3] = fmaf(a2, bv.w, c[2][3]);
    c[3][0] = fmaf(a3, bv.x, c[3][0]); c[3][1] = fmaf(a3, bv.y, c[3][1]);
    c[3][2] = fmaf(a3, bv.z, c[3][2]); c[3][3] = fmaf(a3, bv.w, c[3][3]);
  }

  float x2v[4], y2v[4];
#pragma unroll
  for (int p = 0; p < 4; ++p) x2v[p] = x2[b * NN + i0 + il0 + p];
#pragma unroll
  for (int q = 0; q < 4; ++q) y2v[q] = y2[b * MM + j0 + jl0 + q];
  __syncthreads();
#pragma unroll
  for (int p = 0; p < 4; ++p) {
    float4 r;
    r.x = sqrtf(fmaxf(x2v[p] + y2v[0] - 2.f * c[p][0], 0.f));
    r.y = sqrtf(fmaxf(x2v[p] + y2v[1] - 2.f * c[p][1], 0.f));
    r.z = sqrtf(fmaxf(x2v[p] + y2v[2] - 2.f * c[p][2], 0.f));
    r.w = sqrtf(fmaxf(x2v[p] + y2v[3] - 2.f * c[p][3], 0.f));
    *(float4*)&xs[il0 + p][jl0] = r;
  }
  __syncthreads();

  // stripe-major write-out: unit (lt, tile-col jl=cpp) = 4 bf16 rows
  const int lt = tid & 15, cpp0 = tid >> 4;
  const int l0 = (i0 & 255) >> 2;
  char* bb = dist + (size_t)(b * NBANDS + (i0 >> 8)) * BANDBYTES;
#pragma unroll
  for (int u = 0; u < 4; ++u) {
    int cpp = cpp0 + u * 16;            // tile col 0..63
    int cp = cpp >> 1, par = cpp & 1;
    int l = l0 + lt;
    int t = (j0 >> 1) + cp + l;         // stripe index
    unsigned w0 = pk_bf16x2(xs[lt * 4 + 0][cpp], xs[lt * 4 + 1][cpp]);
    unsigned w1 = pk_bf16x2(xs[lt * 4 + 2][cpp], xs[lt * 4 + 3][cpp]);
    *(uint2*)(bb + (size_t)t * 1024 + l * 16 + par * 8) = make_uint2(w0, w1);
  }
}

// ---------------- DP: 8-band cross-CU pipeline, 1 wave per band ----------------
// ROUND-8 POST-MORTEM: every intra-WG structure lands at ~4-5 cell-slots/cy/CU
// with 8 CUs busy -> the ceiling is parallelism, not scheduling. This round
// splits each batch across 8 WGs (64 CUs total) connected by a global ring
// (release/acquire flags, AGENT scope). Zero barriers, zero LDS in the DP.

#define TICK(S, QV)                                                     \
  {                                                                     \
    float rA = __shfl(rvx, (S), 64);                                    \
    float rB = __shfl(rvy, (S), 64);                                    \
    float sA = __shfl_up(prevA3, 1, 64);                                \
    float sB = __shfl_up(prevB3, 1, 64);                                \
    float upA = isl0 ? rA : sA;                                         \
    float upB = isl0 ? rB : sB;                                         \
    float dA0 = __uint_as_float((QV).x << 16);                          \
    float dA1 = __uint_as_float((QV).x & 0xFFFF0000u);                  \
    float dA2 = __uint_as_float((QV).y << 16);                          \
    float dA3 = __uint_as_float((QV).y & 0xFFFF0000u);                  \
    float dB0 = __uint_as_float((QV).z << 16);                          \
    float dB1 = __uint_as_float((QV).z & 0xFFFF0000u);                  \
    float dB2 = __uint_as_float((QV).w << 16);                          \
    float dB3 = __uint_as_float((QV).w & 0xFFFF0000u);                  \
    float A0 = dA0 + fminf(fminf(P0, topPrev), upA);                    \
    float A1 = dA1 + fminf(fminf(P1, P0), A0);                          \
    float A2 = dA2 + fminf(fminf(P2, P1), A1);                          \
    float A3 = dA3 + fminf(fminf(P3, P2), A2);                          \
    float B0 = dB0 + fminf(fminf(A0, upA), upB);                        \
    float B1 = dB1 + fminf(fminf(A1, A0), B0);                          \
    float B2 = dB2 + fminf(fminf(A2, A1), B1);                          \
    float B3 = dB3 + fminf(fminf(A3, A2), B2);                          \
    P0 = B0; P1 = B1; P2 = B2; P3 = B3;                                 \
    prevA3 = A3; prevB3 = B3; topPrev = upB;                            \
    pubA[S] = A3; pubB[S] = B3;                                         \
  }

#define LOADQ(DST, CB)                                                  \
  {                                                                     \
    const uint4* qn = (const uint4*)(bandbase + ((size_t)(CB) << 14) +  \
                                     ((size_t)lane << 4));              \
    DST[0] = qn[0];     DST[1] = qn[64];    DST[2] = qn[128];           \
    DST[3] = qn[192];   DST[4] = qn[256];   DST[5] = qn[320];           \
    DST[6] = qn[384];   DST[7] = qn[448];   DST[8] = qn[512];           \
    DST[9] = qn[576];   DST[10] = qn[640];  DST[11] = qn[704];          \
    DST[12] = qn[768];  DST[13] = qn[832];  DST[14] = qn[896];          \
    DST[15] = qn[960];                                                  \
  }

#define PUBLISH(CP)                                                     \
  if (lane == 63) {                                                     \
    float4* rp = (float4*)(ringOut + ((size_t)(CP) << 4));              \
    rp[0] = make_float4(pubA[0], pubB[0], pubA[1], pubB[1]);            \
    rp[1] = make_float4(pubA[2], pubB[2], pubA[3], pubB[3]);            \
    rp[2] = make_float4(pubA[4], pubB[4], pubA[5], pubB[5]);            \
    rp[3] = make_float4(pubA[6], pubB[6], pubA[7], pubB[7]);            \
    rp[4] = make_float4(pubA[8], pubB[8], pubA[9], pubB[9]);            \
    rp[5] = make_float4(pubA[10], pubB[10], pubA[11], pubB[11]);        \
    rp[6] = make_float4(pubA[12], pubB[12], pubA[13], pubB[13]);        \
    rp[7] = make_float4(pubA[14], pubB[14], pubA[15], pubB[15]);        \
    __hip_atomic_store(flagOut, (unsigned)((CP) + 1), __ATOMIC_RELEASE, \
                       __HIP_MEMORY_SCOPE_AGENT);                       \
  }

// Chunk order: publish(c-1) [before new loads -> release drain is free] ->
// spin+ring read -> issue next-chunk stripe loads -> 16 ticks on current regs.
#define CHUNK(CUR, NXT, CC)                                             \
  do {                                                                  \
    const int c_ = (CC);                                                \
    if (c_ > 0) PUBLISH(c_ - 1);                                        \
    float rvx = INF, rvy = INF;                                         \
    if (g && c_ <= 63) {                                                \
      const unsigned tgt = (unsigned)(c_ + 5);                          \
      int guard = 0;                                                    \
      while (__hip_atomic_load(flagIn, __ATOMIC_ACQUIRE,                \
                               __HIP_MEMORY_SCOPE_AGENT) < tgt) {       \
        __builtin_amdgcn_s_sleep(8);                                    \
        if (++guard > (1 << 26)) break;                                 \
      }                                                                 \
      if (lane < 16) {                                                  \
        float2 rr = ringIn[(c_ << 4) + 63 + lane];                      \
        rvx = rr.x; rvy = rr.y;                                         \
      }                                                                 \
    }                                                                   \
    LOADQ(NXT, (c_ < 67 ? c_ + 1 : 67));                                \
    TICK(0, CUR[0])  TICK(1, CUR[1])  TICK(2, CUR[2])  TICK(3, CUR[3])  \
    TICK(4, CUR[4])  TICK(5, CUR[5])  TICK(6, CUR[6])  TICK(7, CUR[7])  \
    TICK(8, CUR[8])  TICK(9, CUR[9])  TICK(10, CUR[10]) TICK(11, CUR[11]) \
    TICK(12, CUR[12]) TICK(13, CUR[13]) TICK(14, CUR[14]) TICK(15, CUR[15]) \
  } while (0)

__global__ __launch_bounds__(64, 1) void dp_k(const char* __restrict__ dist,
                                              float2* __restrict__ ring,
                                              unsigned* __restrict__ flags,
                                              float* __restrict__ out) {
  const int bid = blockIdx.x;     // = b*8 + g
  const int g = bid & 7, b = bid >> 3;
  const int lane = threadIdx.x;
  const bool isl0 = (lane == 0);
  const char* bandbase = dist + (size_t)bid * BANDBYTES;
  float2* ringOut = ring + (size_t)bid * RING_SLOTS;
  const float2* ringIn = ring + (size_t)(bid - 1) * RING_SLOTS;  // used iff g>0
  unsigned* flagOut = flags + bid;
  const unsigned* flagIn = flags + (bid - 1);                    // used iff g>0

  float P0 = INF, P1 = INF, P2 = INF, P3 = INF;
  float prevA3 = INF, prevB3 = INF;
  float topPrev = (g == 0 && lane == 0) ? 0.f : INF;  // cell (0,0) injection
  float pubA[16], pubB[16];
  uint4 qa[16], qb[16];

  LOADQ(qa, 0);
  for (int cc = 0; cc < 68; cc += 2) {
    CHUNK(qa, qb, cc);
    CHUNK(qb, qa, cc + 1);
  }
  PUBLISH(67);  // final flag=68 (consumer chunk 63 waits for it)

  // D[2047][2047]: band 7, lane 63, pair 1023 = tick 1086 = chunk 67 step 14
  if (g == 7 && lane == 63) out[b] = pubB[14];
}

extern "C" void kernel_launch(void* const* d_in, const int* in_sizes, int n_in,
                              void* d_out, int out_size, void* d_ws, size_t ws_size,
                              hipStream_t stream) {
  const float* X = (const float*)d_in[0];
  const float* Y = (const float*)d_in[1];
  float* out = (float*)d_out;

  float* x2 = (float*)d_ws;                       // 64KB
  float* y2 = x2 + BB * NN;                       // 64KB
  char* dist = (char*)d_ws + 131072;              // 71.3MB stripe-major bf16
  float2* ring = (float2*)(dist + DIST_BYTES);    // 557KB
  unsigned* flags = (unsigned*)((char*)ring + RING_BYTES);  // 256B

  norms_k<<<dim3((BB * NN + 255) / 256), dim3(256), 0, stream>>>(X, x2, BB * NN);
  norms_k<<<dim3((BB * MM + 255) / 256), dim3(256), 0, stream>>>(Y, y2, BB * MM);
  fill_k<<<dim3(2048), dim3(256), 0, stream>>>((uint4*)dist, (int)(DIST_BYTES / 16));
  hipMemsetAsync(flags, 0, BB * NBANDS * sizeof(unsigned), stream);

  dist_k<<<dim3(MM / 64, NN / 64, BB), dim3(256), 0, stream>>>(X, Y, x2, y2, dist);
  dp_k<<<dim3(BB * NBANDS), dim3(64), 0, stream>>>(dist, ring, flags, out);
}

// Round 10
// 454.012 us; speedup vs baseline: 1.8061x; 1.0054x over previous
//
#include <hip/hip_runtime.h>
#include <hip/hip_bf16.h>

#define BB 8
#define NN 2048
#define MM 2048
#define FF 64
#define INF __builtin_inff()

// ---- pipelined-DP geometry ----
// 8 bands of 256 rows per batch; one 64-lane WG per band; lane l owns rows
// 4l..4l+3 of its band. Tick T: lane l processes column-pair p = T - l
// (cols 2p, 2p+1). Stripe t (1KB) holds, for each lane l, 16B = rows 4l..4l+3
// of cols 2(t-l), 2(t-l)+1  -> the wave's tick-t load is lane-linear.
#define STRIPES 1088                 // ticks: 1024 pairs + 64 skew
#define BANDBYTES (STRIPES * 1024)
#define NBANDS 8
#define DIST_BYTES ((size_t)BB * NBANDS * BANDBYTES)   // 71,303,168
#define RING_SLOTS 1088              // float2 per producer tick
#define RING_BYTES ((size_t)BB * NBANDS * RING_SLOTS * 8)

typedef __hip_bfloat16 bf16;

// pack two f32 -> bf16x2 dword (RNE), a in low half
__device__ __forceinline__ unsigned pk_bf16x2(float a, float b) {
  union { __hip_bfloat162 h; unsigned u; } cv;
  cv.h.x = __float2bfloat16(a);
  cv.h.y = __float2bfloat16(b);
  return cv.u;
}

// ---------------- row norms ----------------
__global__ void norms_k(const float* __restrict__ a, float* __restrict__ o, int rows) {
  int r = blockIdx.x * 256 + threadIdx.x;
  if (r >= rows) return;
  const float4* p = (const float4*)(a + (size_t)r * FF);
  float s = 0.f;
#pragma unroll
  for (int q = 0; q < FF / 4; ++q) {
    float4 v = p[q];
    s = fmaf(v.x, v.x, fmaf(v.y, v.y, fmaf(v.z, v.z, fmaf(v.w, v.w, s))));
  }
  o[r] = s;
}

// ---------------- fill dist with 0x7F7F (bf16 = 3.39e38, INF-like, add-safe)
__global__ void fill_k(uint4* __restrict__ p, int n4) {
  int i = blockIdx.x * 256 + threadIdx.x;
  const int stride = gridDim.x * 256;
  const uint4 v = make_uint4(0x7F7F7F7Fu, 0x7F7F7F7Fu, 0x7F7F7F7Fu, 0x7F7F7F7Fu);
  for (; i < n4; i += stride) p[i] = v;
}

// ---------------- dist tile kernel (unchanged; verified r9) ----------------
__global__ __launch_bounds__(256) void dist_k(const float* __restrict__ X,
                                              const float* __restrict__ Y,
                                              const float* __restrict__ x2,
                                              const float* __restrict__ y2,
                                              char* __restrict__ dist) {
  __shared__ float xs[64][68];
  __shared__ float ysT[64][68];
  const int b = blockIdx.z, i0 = blockIdx.y * 64, j0 = blockIdx.x * 64;
  const int tid = threadIdx.x, tx = tid & 15, ty = tid >> 4;
  const float* Xb = X + ((size_t)b * NN + i0) * FF;
  const float* Yb = Y + ((size_t)b * MM + j0) * FF;
#pragma unroll
  for (int rep = 0; rep < 4; ++rep) {
    int row = rep * 16 + ty;
    float4 vx = *(const float4*)(Xb + row * FF + tx * 4);
    *(float4*)&xs[row][tx * 4] = vx;
    float4 vy = *(const float4*)(Yb + row * FF + tx * 4);
    ysT[tx * 4 + 0][row] = vy.x;
    ysT[tx * 4 + 1][row] = vy.y;
    ysT[tx * 4 + 2][row] = vy.z;
    ysT[tx * 4 + 3][row] = vy.w;
  }
  __syncthreads();

  const int il0 = ty * 4, jl0 = tx * 4;
  float c[4][4] = {};
#pragma unroll
  for (int k = 0; k < FF; ++k) {
    float a0 = xs[il0 + 0][k], a1 = xs[il0 + 1][k], a2 = xs[il0 + 2][k], a3 = xs[il0 + 3][k];
    float4 bv = *(const float4*)&ysT[k][jl0];
    c[0][0] = fmaf(a0, bv.x, c[0][0]); c[0][1] = fmaf(a0, bv.y, c[0][1]);
    c[0][2] = fmaf(a0, bv.z, c[0][2]); c[0][3] = fmaf(a0, bv.w, c[0][3]);
    c[1][0] = fmaf(a1, bv.x, c[1][0]); c[1][1] = fmaf(a1, bv.y, c[1][1]);
    c[1][2] = fmaf(a1, bv.z, c[1][2]); c[1][3] = fmaf(a1, bv.w, c[1][3]);
    c[2][0] = fmaf(a2, bv.x, c[2][0]); c[2][1] = fmaf(a2, bv.y, c[2][1]);
    c[2][2] = fmaf(a2, bv.z, c[2][2]); c[2][3] = fmaf(a2, bv.w, c[2][3]);
    c[3][0] = fmaf(a3, bv.x, c[3][0]); c[3][1] = fmaf(a3, bv.y, c[3][1]);
    c[3][2] = fmaf(a3, bv.z, c[3][2]); c[3][3] = fmaf(a3, bv.w, c[3][3]);
  }

  float x2v[4], y2v[4];
#pragma unroll
  for (int p = 0; p < 4; ++p) x2v[p] = x2[b * NN + i0 + il0 + p];
#pragma unroll
  for (int q = 0; q < 4; ++q) y2v[q] = y2[b * MM + j0 + jl0 + q];
  __syncthreads();
#pragma unroll
  for (int p = 0; p < 4; ++p) {
    float4 r;
    r.x = sqrtf(fmaxf(x2v[p] + y2v[0] - 2.f * c[p][0], 0.f));
    r.y = sqrtf(fmaxf(x2v[p] + y2v[1] - 2.f * c[p][1], 0.f));
    r.z = sqrtf(fmaxf(x2v[p] + y2v[2] - 2.f * c[p][2], 0.f));
    r.w = sqrtf(fmaxf(x2v[p] + y2v[3] - 2.f * c[p][3], 0.f));
    *(float4*)&xs[il0 + p][jl0] = r;
  }
  __syncthreads();

  // stripe-major write-out
  const int lt = tid & 15, cpp0 = tid >> 4;
  const int l0 = (i0 & 255) >> 2;
  char* bb = dist + (size_t)(b * NBANDS + (i0 >> 8)) * BANDBYTES;
#pragma unroll
  for (int u = 0; u < 4; ++u) {
    int cpp = cpp0 + u * 16;            // tile col 0..63
    int cp = cpp >> 1, par = cpp & 1;
    int l = l0 + lt;
    int t = (j0 >> 1) + cp + l;         // stripe index
    unsigned w0 = pk_bf16x2(xs[lt * 4 + 0][cpp], xs[lt * 4 + 1][cpp]);
    unsigned w1 = pk_bf16x2(xs[lt * 4 + 2][cpp], xs[lt * 4 + 3][cpp]);
    *(uint2*)(bb + (size_t)t * 1024 + l * 16 + par * 8) = make_uint2(w0, w1);
  }
}

// ---------------- DP: 8-band cross-CU pipeline, pinned-asm prefetch ----------------
// ROUND-9 POST-MORTEM: plain prefetch loads were sunk to their tick uses
// (VGPR=88 < the 128 needed for qa+qb), exposing ~500cy latency per tick.
// FIX: issue chunk loads as VOLATILE inline-asm global_load_dwordx4 ("=&v")
// -- pinned at the issue point, un-sinkable, un-remat'able. Rule #18: the
// compiler does NOT track asm loads, so an explicit s_waitcnt vmcnt(0) +
// sched_barrier(0) runs once per chunk BEFORE issuing the next loads (the
// current chunk's loads then have had a full chunk of tick-compute cover).

#define TICK(S, QV)                                                     \
  {                                                                     \
    float rA = __shfl(rvx, (S), 64);                                    \
    float rB = __shfl(rvy, (S), 64);                                    \
    float sA = __shfl_up(prevA3, 1, 64);                                \
    float sB = __shfl_up(prevB3, 1, 64);                                \
    float upA = isl0 ? rA : sA;                                         \
    float upB = isl0 ? rB : sB;                                         \
    float dA0 = __uint_as_float((QV).x << 16);                          \
    float dA1 = __uint_as_float((QV).x & 0xFFFF0000u);                  \
    float dA2 = __uint_as_float((QV).y << 16);                          \
    float dA3 = __uint_as_float((QV).y & 0xFFFF0000u);                  \
    float dB0 = __uint_as_float((QV).z << 16);                          \
    float dB1 = __uint_as_float((QV).z & 0xFFFF0000u);                  \
    float dB2 = __uint_as_float((QV).w << 16);                          \
    float dB3 = __uint_as_float((QV).w & 0xFFFF0000u);                  \
    float A0 = dA0 + fminf(fminf(P0, topPrev), upA);                    \
    float A1 = dA1 + fminf(fminf(P1, P0), A0);                          \
    float A2 = dA2 + fminf(fminf(P2, P1), A1);                          \
    float A3 = dA3 + fminf(fminf(P3, P2), A2);                          \
    float B0 = dB0 + fminf(fminf(A0, upA), upB);                        \
    float B1 = dB1 + fminf(fminf(A1, A0), B0);                          \
    float B2 = dB2 + fminf(fminf(A2, A1), B1);                          \
    float B3 = dB3 + fminf(fminf(A3, A2), B2);                          \
    P0 = B0; P1 = B1; P2 = B2; P3 = B3;                                 \
    prevA3 = A3; prevB3 = B3; topPrev = upB;                            \
    pubA[S] = A3; pubB[S] = B3;                                         \
  }

// 4 pinned loads from BASE at stripe stride 1024B; "=&v" early-clobber so
// dests can't alias the address pair.
#define LDA4(A, B, C, D, BASE)                                          \
  asm volatile("global_load_dwordx4 %0, %4, off\n\t"                    \
               "global_load_dwordx4 %1, %4, off offset:1024\n\t"        \
               "global_load_dwordx4 %2, %4, off offset:2048\n\t"        \
               "global_load_dwordx4 %3, %4, off offset:3072"            \
               : "=&v"(A), "=&v"(B), "=&v"(C), "=&v"(D)                 \
               : "v"(BASE)                                              \
               : "memory")

#define LOADQA(DST, CB)                                                 \
  {                                                                     \
    const char* qn_ = bandbase + ((size_t)(CB) << 14) + (lane << 4);    \
    LDA4(DST[0], DST[1], DST[2], DST[3], qn_);                          \
    LDA4(DST[4], DST[5], DST[6], DST[7], qn_ + 4096);                   \
    LDA4(DST[8], DST[9], DST[10], DST[11], qn_ + 8192);                 \
    LDA4(DST[12], DST[13], DST[14], DST[15], qn_ + 12288);              \
  }

#define PUBLISH(CP)                                                     \
  if (lane == 63) {                                                     \
    float4* rp = (float4*)(ringOut + ((size_t)(CP) << 4));              \
    rp[0] = make_float4(pubA[0], pubB[0], pubA[1], pubB[1]);            \
    rp[1] = make_float4(pubA[2], pubB[2], pubA[3], pubB[3]);            \
    rp[2] = make_float4(pubA[4], pubB[4], pubA[5], pubB[5]);            \
    rp[3] = make_float4(pubA[6], pubB[6], pubA[7], pubB[7]);            \
    rp[4] = make_float4(pubA[8], pubB[8], pubA[9], pubB[9]);            \
    rp[5] = make_float4(pubA[10], pubB[10], pubA[11], pubB[11]);        \
    rp[6] = make_float4(pubA[12], pubB[12], pubA[13], pubB[13]);        \
    rp[7] = make_float4(pubA[14], pubB[14], pubA[15], pubB[15]);        \
    __hip_atomic_store(flagOut, (unsigned)((CP) + 1), __ATOMIC_RELEASE, \
                       __HIP_MEMORY_SCOPE_AGENT);                       \
  }

// Chunk: publish(c-1) -> spin/ring read (+pin) -> drain current loads ->
// issue next-chunk pinned loads -> 16 ticks on current regs.
#define CHUNK(CUR, NXT, CC)                                             \
  do {                                                                  \
    const int c_ = (CC);                                                \
    if (c_ > 0) PUBLISH(c_ - 1);                                        \
    float rvx = INF, rvy = INF;                                         \
    if (g && c_ <= 63) {                                                \
      const unsigned tgt = (unsigned)(c_ + 5);                          \
      int guard = 0;                                                    \
      while (__hip_atomic_load(flagIn, __ATOMIC_ACQUIRE,                \
                               __HIP_MEMORY_SCOPE_AGENT) < tgt) {       \
        __builtin_amdgcn_s_sleep(2);                                    \
        if (++guard > (1 << 26)) break;                                 \
      }                                                                 \
      if (lane < 16) {                                                  \
        float2 rr = ringIn[(c_ << 4) + 63 + lane];                      \
        rvx = rr.x; rvy = rr.y;                                         \
      }                                                                 \
    }                                                                   \
    asm volatile("" : "+v"(rvx), "+v"(rvy));  /* ring vals resident */  \
    asm volatile("s_waitcnt vmcnt(0)" ::: "memory");                    \
    __builtin_amdgcn_sched_barrier(0);                                  \
    LOADQA(NXT, (c_ < 67 ? c_ + 1 : 67));                               \
    TICK(0, CUR[0])  TICK(1, CUR[1])  TICK(2, CUR[2])  TICK(3, CUR[3])  \
    TICK(4, CUR[4])  TICK(5, CUR[5])  TICK(6, CUR[6])  TICK(7, CUR[7])  \
    TICK(8, CUR[8])  TICK(9, CUR[9])  TICK(10, CUR[10]) TICK(11, CUR[11]) \
    TICK(12, CUR[12]) TICK(13, CUR[13]) TICK(14, CUR[14]) TICK(15, CUR[15]) \
  } while (0)

__global__ __launch_bounds__(64, 1) void dp_k(const char* __restrict__ dist,
                                              float2* __restrict__ ring,
                                              unsigned* __restrict__ flags,
                                              float* __restrict__ out) {
  const int bid = blockIdx.x;     // = b*8 + g
  const int g = bid & 7, b = bid >> 3;
  const int lane = threadIdx.x;
  const bool isl0 = (lane == 0);
  const char* bandbase = dist + (size_t)bid * BANDBYTES;
  float2* ringOut = ring + (size_t)bid * RING_SLOTS;
  const float2* ringIn = ring + (size_t)(bid - 1) * RING_SLOTS;  // used iff g>0
  unsigned* flagOut = flags + bid;
  const unsigned* flagIn = flags + (bid - 1);                    // used iff g>0

  float P0 = INF, P1 = INF, P2 = INF, P3 = INF;
  float prevA3 = INF, prevB3 = INF;
  float topPrev = (g == 0 && lane == 0) ? 0.f : INF;  // cell (0,0) injection
  float pubA[16], pubB[16];
  uint4 qa[16], qb[16];

  LOADQA(qa, 0);
  for (int cc = 0; cc < 68; cc += 2) {
    CHUNK(qa, qb, cc);
    CHUNK(qb, qa, cc + 1);
  }
  PUBLISH(67);  // final flag=68 (consumer chunk 63 waits for it)

  // D[2047][2047]: band 7, lane 63, pair 1023 = tick 1086 = chunk 67 step 14
  if (g == 7 && lane == 63) out[b] = pubB[14];
}

extern "C" void kernel_launch(void* const* d_in, const int* in_sizes, int n_in,
                              void* d_out, int out_size, void* d_ws, size_t ws_size,
                              hipStream_t stream) {
  const float* X = (const float*)d_in[0];
  const float* Y = (const float*)d_in[1];
  float* out = (float*)d_out;

  float* x2 = (float*)d_ws;                       // 64KB
  float* y2 = x2 + BB * NN;                       // 64KB
  char* dist = (char*)d_ws + 131072;              // 71.3MB stripe-major bf16
  float2* ring = (float2*)(dist + DIST_BYTES);    // 557KB
  unsigned* flags = (unsigned*)((char*)ring + RING_BYTES);  // 256B

  norms_k<<<dim3((BB * NN + 255) / 256), dim3(256), 0, stream>>>(X, x2, BB * NN);
  norms_k<<<dim3((BB * MM + 255) / 256), dim3(256), 0, stream>>>(Y, y2, BB * MM);
  fill_k<<<dim3(2048), dim3(256), 0, stream>>>((uint4*)dist, (int)(DIST_BYTES / 16));
  hipMemsetAsync(flags, 0, BB * NBANDS * sizeof(unsigned), stream);

  dist_k<<<dim3(MM / 64, NN / 64, BB), dim3(256), 0, stream>>>(X, Y, x2, y2, dist);
  dp_k<<<dim3(BB * NBANDS), dim3(64), 0, stream>>>(dist, ring, flags, out);
}